// Round 12
// baseline (4362.824 us; speedup 1.0000x reference)
//
#include <hip/hip_runtime.h>
#include <hip/hip_bf16.h>

#define EPN  512
#define T1N  1024
#define NIN  128
#define HSN  256
#define OUTN 64
#define NBLK 256
#define NTHR 256

typedef __attribute__((ext_vector_type(8))) short bf16x8;
typedef __attribute__((ext_vector_type(4))) short bf16x4;
typedef __attribute__((ext_vector_type(4))) float f32x4;
typedef __attribute__((ext_vector_type(4))) unsigned int u32x4;
typedef unsigned long long u64;

struct KArgs {
  const float *x, *h0, *W_ih, *W_hh, *b_ih, *b_hh, *W_hr, *b_hr, *W_reg, *b_reg;
  float *out;
  ushort *hb;            // [2][1024][256] bf16 recurrent state
  ushort *Ppart;         // [4][16][64][256] bf16, depth-4
  float *Pbuf;           // [4][64][256] f32, depth-4
  float *Sreg;           // [64]
  unsigned int *hflags;  // [16][16]  h-ready per (tgrp,cgrp), monotonic
  unsigned int *pflags;  // [256]     slot-complete per block, monotonic
};

__device__ __forceinline__ float sigm(float v) { return 1.f / (1.f + __expf(-v)); }
__device__ __forceinline__ float tanh_fast(float v) { return 2.f / (1.f + __expf(-2.f * v)) - 1.f; }
__device__ __forceinline__ short f2bf(float f) {
  return (short)__builtin_bit_cast(ushort, __float2bfloat16(f));
}
__device__ __forceinline__ bf16x8 cvt8(f32x4 a, f32x4 b) {
  bf16x8 r;
  r[0]=f2bf(a[0]); r[1]=f2bf(a[1]); r[2]=f2bf(a[2]); r[3]=f2bf(a[3]);
  r[4]=f2bf(b[0]); r[5]=f2bf(b[1]); r[6]=f2bf(b[2]); r[7]=f2bf(b[3]);
  return r;
}

// ---- coherent (L1/L2-bypassing) loads for cross-block data ----
__device__ __forceinline__ bf16x8 ld16h_sc(const ushort* p) {
  bf16x8 v; asm volatile("global_load_dwordx4 %0, %1, off sc0 sc1" : "=v"(v) : "v"(p)); return v;
}
__device__ __forceinline__ f32x4 ld16f_sc(const float* p) {
  f32x4 v; asm volatile("global_load_dwordx4 %0, %1, off sc0 sc1" : "=v"(v) : "v"(p)); return v;
}
__device__ __forceinline__ u32x4 ld16u_sc(const unsigned int* p) {
  u32x4 v; asm volatile("global_load_dwordx4 %0, %1, off sc0 sc1" : "=v"(v) : "v"(p)); return v;
}
__device__ __forceinline__ unsigned int ld2h_sc(const ushort* p) {
  unsigned int v; asm volatile("global_load_ushort %0, %1, off sc0 sc1" : "=v"(v) : "v"(p)); return v;
}
// ---- cross-block data stores as compiler-emitted RETURNING atomic swaps:
// the RMW commits at the coherence point; the vmcnt-ack carries the old value,
// so a following vmcnt(0) proves global visibility (no release fence needed).
__device__ __forceinline__ u64 at8(ushort* p, bf16x4 v) {
  return __hip_atomic_exchange((u64*)p, __builtin_bit_cast(u64, v),
                               __ATOMIC_RELAXED, __HIP_MEMORY_SCOPE_SYSTEM);
}
__device__ __forceinline__ u64 at4(float* p, float v) {
  return (u64)__hip_atomic_exchange((unsigned int*)p, __builtin_bit_cast(unsigned int, v),
                                    __ATOMIC_RELAXED, __HIP_MEMORY_SCOPE_SYSTEM);
}
#define SINK(x) asm volatile("" :: "v"(x))
// plain sc stores: out (host-read after kernel end) and flags (data visibility
// already proven by the atomic drain before the flag store).
__device__ __forceinline__ void st4f_sc(float* p, float v) {
  asm volatile("global_store_dword %0, %1, off sc0 sc1" :: "v"(p), "v"(v) : "memory");
}
__device__ __forceinline__ void st4u_sc(unsigned int* p, unsigned int v) {
  asm volatile("global_store_dword %0, %1, off sc0 sc1" :: "v"(p), "v"(v) : "memory");
}
// plain (cacheable) load for read-only x
__device__ __forceinline__ f32x4 ld16f(const float* p) {
  f32x4 v; asm volatile("global_load_dwordx4 %0, %1, off" : "=v"(v) : "v"(p)); return v;
}
#define WAITV0 do { asm volatile("s_waitcnt vmcnt(0)" ::: "memory"); \
                    __builtin_amdgcn_sched_barrier(0); } while (0)

__device__ __forceinline__ unsigned int min4(u32x4 v) {
  unsigned int m = v[0];
  m = v[1] < m ? v[1] : m; m = v[2] < m ? v[2] : m; m = v[3] < m ? v[3] : m;
  return m;
}
// wave-local flag poll (NO internal __syncthreads): the calling wave's lanes
// [0,nquad) each poll one dwordx4 quad until all >= target; bounded spin.
template<int SLP>
__device__ __forceinline__ void pollflags(const unsigned int* f, int nquad,
                                          unsigned int target, int lane) {
  int spins = 0;
  for (;;) {
    unsigned int m = 0xFFFFFFFFu;
    if (lane < nquad) m = min4(ld16u_sc(f + lane * 4));
    asm volatile("s_waitcnt vmcnt(0)" ::: "memory");
    if (__all((int)(m >= target))) break;
    if (++spins > (1 << 17)) break;          // safety valve: wrong answer, never hang
    __builtin_amdgcn_s_sleep(SLP);
  }
}

#define MFMA(A,B,C) __builtin_amdgcn_mfma_f32_16x16x32_bf16(A, B, C, 0, 0, 0)

// ---------------- setup kernel (ordinary launch #1) ----------------
__global__ void gru_setup(KArgs a) {
  const int gtid = blockIdx.x * blockDim.x + threadIdx.x;
  const int gsz = gridDim.x * blockDim.x;
  if (gtid < 512) { if (gtid < 256) a.hflags[gtid] = 0; else a.pflags[gtid - 256] = 0; }
  for (int i = gtid; i < T1N * HSN; i += gsz)
    a.hb[i] = __builtin_bit_cast(ushort, __float2bfloat16(a.h0[i]));  // parity 0
  if (gtid < OUTN) {
    float ssum = 0.f; const float* wr = a.W_reg + (size_t)gtid * T1N;
    for (int t = 0; t < T1N; ++t) ssum += wr[t];
    a.Sreg[gtid] = ssum;
  }
}

// ---------------- main persistent kernel (ordinary launch #2) ----------------
__global__ __launch_bounds__(NTHR, 1) void gru12(KArgs a) {
  const int bid = blockIdx.x, tid = threadIdx.x;

  // XCD clustering: bid%8 = tgrp%8 for all 16 mates of a tgrp -> x/h L2 reuse.
  const int tgrp = bid & 15, cgrp = bid >> 4;
  const int t0 = tgrp * 64, c0 = cgrp * 16;

  __shared__ __align__(16) short WtL[64 * 80];   // 10 KB: W_reg tile (bf16, stride 80)
  __shared__ __align__(16) short hT [16 * 80];   // 2.5 KB: h_new^T tile
  __shared__ float cpart[256];

  // ---- W_reg tile -> LDS (bf16) ----
  {
    int o = tid >> 2, seg = tid & 3;
    const float* wr = a.W_reg + (size_t)o * T1N + t0 + seg * 16;
    bf16x8 p0, p1;
    #pragma unroll
    for (int j = 0; j < 8; ++j) p0[j] = f2bf(wr[j]);
    #pragma unroll
    for (int j = 0; j < 8; ++j) p1[j] = f2bf(wr[8 + j]);
    *(bf16x8*)&WtL[o * 80 + seg * 16]     = p0;
    *(bf16x8*)&WtL[o * 80 + seg * 16 + 8] = p1;
  }
  __syncthreads();

  // per-lane constants
  const int lane = tid & 63, wv_ = tid >> 6;     // 4 waves
  const int cl = lane & 15, kg = lane >> 4;
  const int tb = t0 + wv_ * 16;
  const int c  = c0 + cl;
  const float bR  = a.b_ih[c] + a.b_hh[c];
  const float bZ  = a.b_ih[HSN + c] + a.b_hh[HSN + c];
  const float bIN = a.b_ih[2*HSN + c];
  const float bHN = a.b_hh[2*HSN + c];

  // ---- recurrent weights -> REGISTERS (constant all 512 steps) ----
  bf16x8 whR[8], whZ[8], whN[8];                 // W_hh fragments, K=256
  #pragma unroll
  for (int ks = 0; ks < 8; ++ks) {
    const float* pr = a.W_hh + (size_t)(0*HSN + c) * HSN + ks * 32 + kg * 8;
    const float* pz = a.W_hh + (size_t)(1*HSN + c) * HSN + ks * 32 + kg * 8;
    const float* pn = a.W_hh + (size_t)(2*HSN + c) * HSN + ks * 32 + kg * 8;
    whR[ks] = cvt8(*(const f32x4*)pr, *(const f32x4*)(pr + 4));
    whZ[ks] = cvt8(*(const f32x4*)pz, *(const f32x4*)(pz + 4));
    whN[ks] = cvt8(*(const f32x4*)pn, *(const f32x4*)(pn + 4));
  }
  bf16x8 wxR[4], wxZ[4], wxN[4];                 // W_ih fragments, K=128
  #pragma unroll
  for (int ks = 0; ks < 4; ++ks) {
    const float* pr = a.W_ih + (size_t)(0*HSN + c) * NIN + ks * 32 + kg * 8;
    const float* pz = a.W_ih + (size_t)(1*HSN + c) * NIN + ks * 32 + kg * 8;
    const float* pn = a.W_ih + (size_t)(2*HSN + c) * NIN + ks * 32 + kg * 8;
    wxR[ks] = cvt8(*(const f32x4*)pr, *(const f32x4*)(pr + 4));
    wxZ[ks] = cvt8(*(const f32x4*)pz, *(const f32x4*)(pz + 4));
    wxN[ks] = cvt8(*(const f32x4*)pn, *(const f32x4*)(pn + 4));
  }

  // C-phase constants
  const int n0 = bid >> 1, oh = (bid & 1) * 32;
  const int oo = tid & 31, part = tid >> 5;
  f32x4 whr[8];
  #pragma unroll
  for (int j = 0; j < 8; ++j) whr[j] = *(const f32x4*)&a.W_hr[(size_t)n0 * HSN + part * 32 + j * 4];
  const float cb = a.b_hr[n0];
  const float sregv = a.Sreg[oh + oo];           // from setup launch
  const float bregv = a.b_reg[oh + oo];

  // fp32 recurrent state for this block's own (t,c) tile lives in registers
  float hp[4];
  #pragma unroll
  for (int r = 0; r < 4; ++r) hp[r] = a.h0[(size_t)(tb + kg * 4 + r) * HSN + c];

  // gi(0) = x(0) @ W_ih^T -> registers
  f32x4 giR = {0,0,0,0}, giZ = {0,0,0,0}, giN = {0,0,0,0};
  {
    const float* xrow = a.x + (size_t)(tb + cl) * NIN + kg * 8;
    #pragma unroll
    for (int ks = 0; ks < 4; ++ks) {
      f32x4 x0 = *(const f32x4*)(xrow + ks * 32);
      f32x4 x1 = *(const f32x4*)(xrow + ks * 32 + 4);
      bf16x8 af = cvt8(x0, x1);
      giR = MFMA(af, wxR[ks], giR); giZ = MFMA(af, wxZ[ks], giZ); giN = MFMA(af, wxN[ks], giN);
    }
  }

  // ---------------- main pipeline: EPN+4 slots ----------------
  // slot s: h(s+1) produced; Ppart(s) stored; P-reduce(s-2); C/out(s-4).
  for (int s = 0; s < EPN + 4; ++s) {
    const ushort* hb_r = a.hb + (size_t)(s & 1) * (T1N * HSN);
    ushort*       hb_w = a.hb + (size_t)((s + 1) & 1) * (T1N * HSN);

    // ---- top waits, CONCURRENT on different waves ----
    // wave0: all-blocks pflags >= s-1 (gates Ppart/Pbuf reads AND overwrites;
    //        1-slot slack -> first-poll success in steady state)
    // wave1: 16 mate hflags >= s (gates h(s) reads)
    if (wv_ == 0) {
      if (s >= 2) pollflags<2>(a.pflags, 64, (unsigned)(s - 1), lane);
    } else if (wv_ == 1) {
      if (s >= 1 && s < EPN) pollflags<1>(a.hflags + tgrp * 16, 4, (unsigned)s, lane);
    }
    __syncthreads();

    // ---- batch-issue ALL loads for this slot: h, rv, cv, x; ONE safe wait ----
    bf16x8 hfr[8];
    if (s < EPN) {
      const ushort* hrow = hb_r + (size_t)(tb + cl) * HSN + kg * 8;
      #pragma unroll
      for (int ks = 0; ks < 8; ++ks) hfr[ks] = ld16h_sc(hrow + ks * 32);
    }
    unsigned int rv[16];
    const bool hasR = (s >= 2 && s < EPN + 2);
    if (tid < 64 && hasR) {
      const ushort* pp = a.Ppart + (size_t)((s - 2) & 3) * (16 * 16384) + bid * 64 + tid;
      #pragma unroll
      for (int j = 0; j < 16; ++j) rv[j] = ld2h_sc(pp + (size_t)j * 16384);
    }
    f32x4 cv[8];
    if (s >= 4) {
      const float* pb = a.Pbuf + (size_t)((s - 4) & 3) * 16384 + (size_t)(oh + oo) * 256 + part * 32;
      #pragma unroll
      for (int j = 0; j < 8; ++j) cv[j] = ld16f_sc(pb + j * 4);
    }
    f32x4 xa[4], xb[4];
    const bool hasX = (s + 1 < EPN);
    if (hasX) {
      const float* xrow = a.x + ((size_t)(s + 1) * T1N + tb + cl) * NIN + kg * 8;
      #pragma unroll
      for (int ks = 0; ks < 4; ++ks) {
        xa[ks] = ld16f(xrow + ks * 32);
        xb[ks] = ld16f(xrow + ks * 32 + 4);
      }
    }
    WAITV0;

    // ---- h-GEMM (24 MFMA, register operands) + epilogue -> hT ----
    if (s < EPN) {
      f32x4 accR = {0,0,0,0}, accZ = {0,0,0,0}, accN = {0,0,0,0};
      #pragma unroll
      for (int ks = 0; ks < 8; ++ks) {
        accR = MFMA(hfr[ks], whR[ks], accR);
        accZ = MFMA(hfr[ks], whZ[ks], accZ);
        accN = MFMA(hfr[ks], whN[ks], accN);
      }
      bf16x4 hpk;
      #pragma unroll
      for (int r = 0; r < 4; ++r) {
        float rr = sigm(accR[r] + giR[r] + bR);
        float zz = sigm(accZ[r] + giZ[r] + bZ);
        float nn = tanh_fast(giN[r] + bIN + rr * (accN[r] + bHN));
        float hn = (1.f - zz) * nn + zz * hp[r];
        hp[r] = hn;
        hpk[r] = f2bf(hn);
      }
      *(bf16x4*)&hT[cl * 80 + wv_ * 16 + kg * 4] = hpk;   // h^T tile [16c][64t]
    }
    __syncthreads();                                       // hT visible

    // ---- h -> global via returning atomic swap; drain; EARLY hflag publish ----
    if (s < EPN) {
      int th = tid >> 2, c4 = (tid & 3) * 4;
      bf16x4 hpk2;
      #pragma unroll
      for (int j = 0; j < 4; ++j) hpk2[j] = hT[(c4 + j) * 80 + th];
      u64 hold = at8(hb_w + (size_t)(t0 + th) * HSN + c0 + c4, hpk2);
      SINK(hold);                                          // force returning form
    }
    WAITV0;
    __syncthreads();                                       // all waves' atomics committed
    if (s < EPN && tid == 0) st4u_sc(a.hflags + tgrp * 16 + cgrp, (unsigned)(s + 1));

    // ---- shadow work (mates' polls overlap this) ----
    u64 pdum = 0;
    // B: Ppart(s) via MFMA on own h_new
    if (s < EPN) {
      f32x4 pacc = {0,0,0,0};
      #pragma unroll
      for (int ks = 0; ks < 2; ++ks) {
        bf16x8 pa = *(const bf16x8*)&hT[cl * 80 + ks * 32 + kg * 8];
        bf16x8 pb = *(const bf16x8*)&WtL[(wv_ * 16 + cl) * 80 + ks * 32 + kg * 8];
        pacc = MFMA(pa, pb, pacc);
      }
      bf16x4 pk;
      #pragma unroll
      for (int r = 0; r < 4; ++r) pk[r] = f2bf(pacc[r]);
      pdum ^= at8(a.Ppart + ((size_t)(s & 3) * 16 + tgrp) * 16384 + (size_t)(wv_ * 16 + cl) * 256 + c0 + kg * 4, pk);
    }
    // P-reduce(s-2)
    if (tid < 64 && hasR) {
      float sum = 0.f;
      #pragma unroll
      for (int j = 0; j < 16; ++j) sum += __builtin_bit_cast(float, rv[j] << 16);
      pdum ^= at4(a.Pbuf + (size_t)((s - 2) & 3) * 16384 + bid * 64 + tid, sum);
    }
    // C partial (s-4)
    if (s >= 4) {
      float cacc = 0.f;
      #pragma unroll
      for (int j = 0; j < 8; ++j)
        cacc += whr[j][0]*cv[j][0] + whr[j][1]*cv[j][1] + whr[j][2]*cv[j][2] + whr[j][3]*cv[j][3];
      cpart[part * 32 + oo] = cacc;
    }
    // gi-GEMM for s+1 (register-only)
    f32x4 giR2 = {0,0,0,0}, giZ2 = {0,0,0,0}, giN2 = {0,0,0,0};
    if (hasX) {
      #pragma unroll
      for (int ks = 0; ks < 4; ++ks) {
        bf16x8 af = cvt8(xa[ks], xb[ks]);
        giR2 = MFMA(af, wxR[ks], giR2); giZ2 = MFMA(af, wxZ[ks], giZ2); giN2 = MFMA(af, wxN[ks], giN2);
      }
    }
    giR = giR2; giZ = giZ2; giN = giN2;

    // ---- single end-of-slot drain: P atomics committed, then publish ----
    SINK(pdum);
    WAITV0;
    __syncthreads();                                       // cpart + all drains done
    if (s >= 4 && tid < 32) {                              // final out(s-4)
      float v = cb * sregv + bregv;
      #pragma unroll
      for (int p = 0; p < 8; ++p) v += cpart[p * 32 + tid];
      st4f_sc(a.out + ((size_t)(s - 4) * NIN + n0) * OUTN + oh + tid, v);
    }
    if (tid == 0) st4u_sc(a.pflags + bid, (unsigned)(s + 1));
  }
}

extern "C" void kernel_launch(void* const* d_in, const int* in_sizes, int n_in,
                              void* d_out, int out_size, void* d_ws, size_t ws_size,
                              hipStream_t stream) {
  KArgs a;
  a.x     = (const float*)d_in[0];
  a.h0    = (const float*)d_in[1];
  a.W_ih  = (const float*)d_in[2];
  a.W_hh  = (const float*)d_in[3];
  a.b_ih  = (const float*)d_in[4];
  a.b_hh  = (const float*)d_in[5];
  a.W_hr  = (const float*)d_in[6];
  a.b_hr  = (const float*)d_in[7];
  a.W_reg = (const float*)d_in[8];
  a.b_reg = (const float*)d_in[9];
  a.out   = (float*)d_out;

  // Total footprint ~3.26 MB (proven-available). Flags at the FRONT.
  char* w = (char*)d_ws;
  a.hflags = (unsigned int*)w; w += 256 * 4;                           // 1 KB
  a.pflags = (unsigned int*)w; w += 256 * 4;                           // 1 KB
  a.Sreg   = (float*)w;        w += 256;                               // 256 B
  a.hb     = (ushort*)w;       w += (size_t)2 * T1N * HSN * 2;         // 1 MB
  a.Pbuf   = (float*)w;        w += (size_t)4 * 16384 * 4;             // 256 KB
  a.Ppart  = (ushort*)w;       w += (size_t)4 * 16 * 16384 * 2;        // 2 MB

  hipLaunchKernelGGL(gru_setup, dim3(64), dim3(NTHR), 0, stream, a);
  hipLaunchKernelGGL(gru12, dim3(NBLK), dim3(NTHR), 0, stream, a);
}

// Round 13
// 3757.409 us; speedup vs baseline: 1.1611x; 1.1611x over previous
//
#include <hip/hip_runtime.h>
#include <hip/hip_bf16.h>

#define EPN  512
#define T1N  1024
#define NIN  128
#define HSN  256
#define OUTN 64
#define NBLK 256
#define NTHR 512   // 8 waves: 0-3 = H-group (recurrence), 4-7 = P-group (projection)

typedef __attribute__((ext_vector_type(8))) short bf16x8;
typedef __attribute__((ext_vector_type(4))) short bf16x4;
typedef __attribute__((ext_vector_type(4))) float f32x4;
typedef __attribute__((ext_vector_type(4))) unsigned int u32x4;
typedef unsigned long long u64;

struct KArgs {
  const float *x, *h0, *W_ih, *W_hh, *b_ih, *b_hh, *W_hr, *b_hr, *W_reg, *b_reg;
  float *out;
  ushort *hb;            // [2][1024][256] bf16 recurrent state
  ushort *Ppart;         // [4][16][64][256] bf16, depth-4
  float *Pbuf;           // [4][64][256] f32, depth-4
  float *Sreg;           // [64]
  unsigned int *hflags;  // [16][16]  h-ready per (tgrp,cgrp), monotonic
  unsigned int *pflags;  // [256]     slot-complete per block, monotonic
};

__device__ __forceinline__ float sigm(float v) { return 1.f / (1.f + __expf(-v)); }
__device__ __forceinline__ float tanh_fast(float v) { return 2.f / (1.f + __expf(-2.f * v)) - 1.f; }
__device__ __forceinline__ short f2bf(float f) {
  return (short)__builtin_bit_cast(ushort, __float2bfloat16(f));
}
__device__ __forceinline__ bf16x8 cvt8(f32x4 a, f32x4 b) {
  bf16x8 r;
  r[0]=f2bf(a[0]); r[1]=f2bf(a[1]); r[2]=f2bf(a[2]); r[3]=f2bf(a[3]);
  r[4]=f2bf(b[0]); r[5]=f2bf(b[1]); r[6]=f2bf(b[2]); r[7]=f2bf(b[3]);
  return r;
}

// ---- coherent (L1/L2-bypassing) loads for cross-block data ----
__device__ __forceinline__ bf16x8 ld16h_sc(const ushort* p) {
  bf16x8 v; asm volatile("global_load_dwordx4 %0, %1, off sc0 sc1" : "=v"(v) : "v"(p)); return v;
}
__device__ __forceinline__ f32x4 ld16f_sc(const float* p) {
  f32x4 v; asm volatile("global_load_dwordx4 %0, %1, off sc0 sc1" : "=v"(v) : "v"(p)); return v;
}
__device__ __forceinline__ u32x4 ld16u_sc(const unsigned int* p) {
  u32x4 v; asm volatile("global_load_dwordx4 %0, %1, off sc0 sc1" : "=v"(v) : "v"(p)); return v;
}
__device__ __forceinline__ unsigned int ld2h_sc(const ushort* p) {
  unsigned int v; asm volatile("global_load_ushort %0, %1, off sc0 sc1" : "=v"(v) : "v"(p)); return v;
}
// ---- cross-block data stores as compiler-emitted RETURNING atomic swaps:
// RMW commits at the coherence point; vmcnt-ack carries the old value, so a
// following vmcnt(0) proves global visibility (proven in rounds 11/12).
__device__ __forceinline__ u64 at8(ushort* p, bf16x4 v) {
  return __hip_atomic_exchange((u64*)p, __builtin_bit_cast(u64, v),
                               __ATOMIC_RELAXED, __HIP_MEMORY_SCOPE_SYSTEM);
}
__device__ __forceinline__ u64 at4(float* p, float v) {
  return (u64)__hip_atomic_exchange((unsigned int*)p, __builtin_bit_cast(unsigned int, v),
                                    __ATOMIC_RELAXED, __HIP_MEMORY_SCOPE_SYSTEM);
}
#define SINK(x) asm volatile("" :: "v"(x))
__device__ __forceinline__ void st4f_sc(float* p, float v) {
  asm volatile("global_store_dword %0, %1, off sc0 sc1" :: "v"(p), "v"(v) : "memory");
}
__device__ __forceinline__ void st4u_sc(unsigned int* p, unsigned int v) {
  asm volatile("global_store_dword %0, %1, off sc0 sc1" :: "v"(p), "v"(v) : "memory");
}
__device__ __forceinline__ f32x4 ld16f(const float* p) {
  f32x4 v; asm volatile("global_load_dwordx4 %0, %1, off" : "=v"(v) : "v"(p)); return v;
}
#define WAITV0 do { asm volatile("s_waitcnt vmcnt(0)" ::: "memory"); \
                    __builtin_amdgcn_sched_barrier(0); } while (0)
// Raw block barrier usable in wave-divergent (but count-matched) control flow.
#define BAR do { asm volatile("s_waitcnt lgkmcnt(0)" ::: "memory"); \
                 __builtin_amdgcn_s_barrier(); \
                 asm volatile("" ::: "memory"); \
                 __builtin_amdgcn_sched_barrier(0); } while (0)

__device__ __forceinline__ unsigned int min4(u32x4 v) {
  unsigned int m = v[0];
  m = v[1] < m ? v[1] : m; m = v[2] < m ? v[2] : m; m = v[3] < m ? v[3] : m;
  return m;
}
// wave-local flag poll (no internal barrier); bounded spin.
template<int SLP>
__device__ __forceinline__ void pollflags(const unsigned int* f, int nquad,
                                          unsigned int target, int lane) {
  int spins = 0;
  for (;;) {
    unsigned int m = 0xFFFFFFFFu;
    if (lane < nquad) m = min4(ld16u_sc(f + lane * 4));
    asm volatile("s_waitcnt vmcnt(0)" ::: "memory");
    if (__all((int)(m >= target))) break;
    if (++spins > (1 << 17)) break;          // safety valve: wrong answer, never hang
    __builtin_amdgcn_s_sleep(SLP);
  }
}

#define MFMA(A,B,C) __builtin_amdgcn_mfma_f32_16x16x32_bf16(A, B, C, 0, 0, 0)

// ---------------- setup kernel (ordinary launch #1) ----------------
__global__ void gru_setup(KArgs a) {
  const int gtid = blockIdx.x * blockDim.x + threadIdx.x;
  const int gsz = gridDim.x * blockDim.x;
  if (gtid < 512) { if (gtid < 256) a.hflags[gtid] = 0; else a.pflags[gtid - 256] = 0; }
  for (int i = gtid; i < T1N * HSN; i += gsz)
    a.hb[i] = __builtin_bit_cast(ushort, __float2bfloat16(a.h0[i]));  // parity 0
  if (gtid < OUTN) {
    float ssum = 0.f; const float* wr = a.W_reg + (size_t)gtid * T1N;
    for (int t = 0; t < T1N; ++t) ssum += wr[t];
    a.Sreg[gtid] = ssum;
  }
}

// ---------------- main persistent kernel: wave-specialized ----------------
// slot s: H-group: h(s+1) = GRU(h(s), gi(s)); P-group: gi(s+1), Ppart(s-1),
// P-reduce gen s-3, C/out epoch s-5. 3 matched barriers per slot per group.
__global__ __launch_bounds__(NTHR, 2) void gru13(KArgs a) {
  const int bid = blockIdx.x, tid = threadIdx.x;
  const int tgrp = bid & 15, cgrp = bid >> 4;    // bid%8 == tgrp%8 -> XCD clustering
  const int t0 = tgrp * 64, c0 = cgrp * 16;

  __shared__ __align__(16) short WtL[64 * 80];   // 10 KB  W_reg tile (P)
  __shared__ __align__(16) short hT2[2][16 * 80];// 5 KB   h_new^T, double-buffered
  __shared__ __align__(16) f32x4 giL[2][3][256]; // 24 KB  gi handoff, double-buffered
  __shared__ float cpart[256];

  if (tid < 256) {
    // ================= H-group: the serial recurrence =================
    const int lane = tid & 63, wv_ = tid >> 6;
    const int cl = lane & 15, kg = lane >> 4;
    const int tb = t0 + wv_ * 16;
    const int c  = c0 + cl;
    const float bR  = a.b_ih[c] + a.b_hh[c];
    const float bZ  = a.b_ih[HSN + c] + a.b_hh[HSN + c];
    const float bIN = a.b_ih[2*HSN + c];
    const float bHN = a.b_hh[2*HSN + c];

    bf16x8 whR[8], whZ[8], whN[8];               // W_hh fragments, K=256 (96 VGPR)
    #pragma unroll
    for (int ks = 0; ks < 8; ++ks) {
      const float* pr = a.W_hh + (size_t)(0*HSN + c) * HSN + ks * 32 + kg * 8;
      const float* pz = a.W_hh + (size_t)(1*HSN + c) * HSN + ks * 32 + kg * 8;
      const float* pn = a.W_hh + (size_t)(2*HSN + c) * HSN + ks * 32 + kg * 8;
      whR[ks] = cvt8(*(const f32x4*)pr, *(const f32x4*)(pr + 4));
      whZ[ks] = cvt8(*(const f32x4*)pz, *(const f32x4*)(pz + 4));
      whN[ks] = cvt8(*(const f32x4*)pn, *(const f32x4*)(pn + 4));
    }
    float hp[4];
    #pragma unroll
    for (int r = 0; r < 4; ++r) hp[r] = a.h0[(size_t)(tb + kg * 4 + r) * HSN + c];

    for (int s = 0; s < EPN + 5; ++s) {
      if (tid < 64 && s >= 1 && s < EPN)
        pollflags<1>(a.hflags + tgrp * 16, 4, (unsigned)s, tid);
      BAR;   // TOP: hwait (this group) + pwait (P-group) both hold

      if (s < EPN) {
        bf16x8 hfr[8];
        const ushort* hrow = a.hb + (size_t)(s & 1) * (T1N * HSN)
                           + (size_t)(tb + cl) * HSN + kg * 8;
        #pragma unroll
        for (int ks = 0; ks < 8; ++ks) hfr[ks] = ld16h_sc(hrow + ks * 32);
        WAITV0;
        f32x4 accR = {0,0,0,0}, accZ = {0,0,0,0}, accN = {0,0,0,0};
        #pragma unroll
        for (int ks = 0; ks < 8; ++ks) {
          accR = MFMA(hfr[ks], whR[ks], accR);
          accZ = MFMA(hfr[ks], whZ[ks], accZ);
          accN = MFMA(hfr[ks], whN[ks], accN);
        }
        f32x4 g0 = giL[s & 1][0][tid];             // gi(s) from P-group (slot s-1)
        f32x4 g1 = giL[s & 1][1][tid];
        f32x4 g2 = giL[s & 1][2][tid];
        bf16x4 hpk;
        #pragma unroll
        for (int r = 0; r < 4; ++r) {
          float rr = sigm(accR[r] + g0[r] + bR);
          float zz = sigm(accZ[r] + g1[r] + bZ);
          float nn = tanh_fast(g2[r] + bIN + rr * (accN[r] + bHN));
          float hn = (1.f - zz) * nn + zz * hp[r];
          hp[r] = hn;
          hpk[r] = f2bf(hn);
        }
        *(bf16x4*)&hT2[s & 1][cl * 80 + wv_ * 16 + kg * 4] = hpk;
      }
      BAR;   // MID: hT2[s&1] complete

      if (s < EPN) {
        int th = tid >> 2, c4 = (tid & 3) * 4;
        bf16x4 hpk2;
        #pragma unroll
        for (int j = 0; j < 4; ++j) hpk2[j] = hT2[s & 1][(c4 + j) * 80 + th];
        u64 hold = at8(a.hb + (size_t)((s + 1) & 1) * (T1N * HSN)
                       + (size_t)(t0 + th) * HSN + c0 + c4, hpk2);
        SINK(hold);
      }
      WAITV0;  // h atomics committed (this wave)
      BAR;     // END: all waves drained
      if (s < EPN && tid == 0)
        st4u_sc(a.hflags + tgrp * 16 + cgrp, (unsigned)(s + 1));
    }
  } else {
    // ================= P-group: gi + projection pipeline =================
    const int tp = tid - 256;
    const int lane = tp & 63, wvp = tp >> 6;
    const int clp = lane & 15, kgp = lane >> 4;
    const int tbp = t0 + wvp * 16;
    const int cp  = c0 + clp;

    bf16x8 wxR[4], wxZ[4], wxN[4];               // W_ih fragments, K=128 (48 VGPR)
    #pragma unroll
    for (int ks = 0; ks < 4; ++ks) {
      const float* pr = a.W_ih + (size_t)(0*HSN + cp) * NIN + ks * 32 + kgp * 8;
      const float* pz = a.W_ih + (size_t)(1*HSN + cp) * NIN + ks * 32 + kgp * 8;
      const float* pn = a.W_ih + (size_t)(2*HSN + cp) * NIN + ks * 32 + kgp * 8;
      wxR[ks] = cvt8(*(const f32x4*)pr, *(const f32x4*)(pr + 4));
      wxZ[ks] = cvt8(*(const f32x4*)pz, *(const f32x4*)(pz + 4));
      wxN[ks] = cvt8(*(const f32x4*)pn, *(const f32x4*)(pn + 4));
    }
    // W_reg tile -> LDS (bf16)
    {
      int o = tp >> 2, seg = tp & 3;
      const float* wr = a.W_reg + (size_t)o * T1N + t0 + seg * 16;
      bf16x8 p0, p1;
      #pragma unroll
      for (int j = 0; j < 8; ++j) p0[j] = f2bf(wr[j]);
      #pragma unroll
      for (int j = 0; j < 8; ++j) p1[j] = f2bf(wr[8 + j]);
      *(bf16x8*)&WtL[o * 80 + seg * 16]     = p0;
      *(bf16x8*)&WtL[o * 80 + seg * 16 + 8] = p1;
    }
    const int n0 = bid >> 1, oh = (bid & 1) * 32;
    const int oo = tp & 31, part = tp >> 5;
    f32x4 whr[8];
    #pragma unroll
    for (int j = 0; j < 8; ++j) whr[j] = *(const f32x4*)&a.W_hr[(size_t)n0 * HSN + part * 32 + j * 4];
    const float cb    = a.b_hr[n0];
    const float sregv = a.Sreg[oh + oo];
    const float bregv = a.b_reg[oh + oo];

    // gi(0) -> giL[0] (consumed by H at slot 0, after TOP(0))
    {
      const float* xrow = a.x + (size_t)(tbp + clp) * NIN + kgp * 8;
      f32x4 r0 = {0,0,0,0}, r1 = {0,0,0,0}, r2 = {0,0,0,0};
      #pragma unroll
      for (int ks = 0; ks < 4; ++ks) {
        f32x4 x0 = *(const f32x4*)(xrow + ks * 32);
        f32x4 x1 = *(const f32x4*)(xrow + ks * 32 + 4);
        bf16x8 af = cvt8(x0, x1);
        r0 = MFMA(af, wxR[ks], r0); r1 = MFMA(af, wxZ[ks], r1); r2 = MFMA(af, wxN[ks], r2);
      }
      giL[0][0][tp] = r0; giL[0][1][tp] = r1; giL[0][2][tp] = r2;
    }

    for (int s = 0; s < EPN + 5; ++s) {
      if (tp < 64 && s >= 2)
        pollflags<2>(a.pflags, 64, (unsigned)(s - 1), tp);
      BAR;   // TOP

      // batch-issue P loads (all gated by PREVIOUS slot's pwait)
      unsigned int rv[16];
      const bool hasR = (s >= 3 && s <= EPN + 2);    // P-reduce gen s-3
      if (tp < 64 && hasR) {
        const ushort* pp = a.Ppart + (size_t)((s - 3) & 3) * (16 * 16384) + bid * 64 + tp;
        #pragma unroll
        for (int j = 0; j < 16; ++j) rv[j] = ld2h_sc(pp + (size_t)j * 16384);
      }
      f32x4 cv[8];
      const bool hasC = (s >= 5 && s < EPN + 5);     // C epoch s-5
      if (hasC) {
        const float* pb = a.Pbuf + (size_t)((s - 5) & 3) * 16384 + (size_t)(oh + oo) * 256 + part * 32;
        #pragma unroll
        for (int j = 0; j < 8; ++j) cv[j] = ld16f_sc(pb + j * 4);
      }
      f32x4 xa[4], xb[4];
      const bool hasX = (s + 1 < EPN);
      if (hasX) {
        const float* xrow = a.x + ((size_t)(s + 1) * T1N + tbp + clp) * NIN + kgp * 8;
        #pragma unroll
        for (int ks = 0; ks < 4; ++ks) {
          xa[ks] = ld16f(xrow + ks * 32);
          xb[ks] = ld16f(xrow + ks * 32 + 4);
        }
      }
      WAITV0;

      u64 pdum = 0;
      // B: Ppart(s-1) from hT2[(s-1)&1] (written by H last slot; stable now)
      if (s >= 1 && s <= EPN) {
        f32x4 pacc = {0,0,0,0};
        #pragma unroll
        for (int ks = 0; ks < 2; ++ks) {
          bf16x8 pa = *(const bf16x8*)&hT2[(s - 1) & 1][clp * 80 + ks * 32 + kgp * 8];
          bf16x8 pb = *(const bf16x8*)&WtL[(wvp * 16 + clp) * 80 + ks * 32 + kgp * 8];
          pacc = MFMA(pa, pb, pacc);
        }
        bf16x4 pk;
        #pragma unroll
        for (int r = 0; r < 4; ++r) pk[r] = f2bf(pacc[r]);
        pdum ^= at8(a.Ppart + ((size_t)((s - 1) & 3) * 16 + tgrp) * 16384
                    + (size_t)(wvp * 16 + clp) * 256 + c0 + kgp * 4, pk);
      }
      BAR;   // MID

      // P-reduce gen s-3
      if (tp < 64 && hasR) {
        float sum = 0.f;
        #pragma unroll
        for (int j = 0; j < 16; ++j) sum += __builtin_bit_cast(float, rv[j] << 16);
        pdum ^= at4(a.Pbuf + (size_t)((s - 3) & 3) * 16384 + bid * 64 + tp, sum);
      }
      // C partial, epoch s-5
      if (hasC) {
        float cacc = 0.f;
        #pragma unroll
        for (int j = 0; j < 8; ++j)
          cacc += whr[j][0]*cv[j][0] + whr[j][1]*cv[j][1] + whr[j][2]*cv[j][2] + whr[j][3]*cv[j][3];
        cpart[tp] = cacc;
      }
      // gi(s+1) -> giL[(s+1)&1]
      if (hasX) {
        f32x4 r0 = {0,0,0,0}, r1 = {0,0,0,0}, r2 = {0,0,0,0};
        #pragma unroll
        for (int ks = 0; ks < 4; ++ks) {
          bf16x8 af = cvt8(xa[ks], xb[ks]);
          r0 = MFMA(af, wxR[ks], r0); r1 = MFMA(af, wxZ[ks], r1); r2 = MFMA(af, wxN[ks], r2);
        }
        giL[(s + 1) & 1][0][tp] = r0; giL[(s + 1) & 1][1][tp] = r1; giL[(s + 1) & 1][2][tp] = r2;
      }
      SINK(pdum);
      WAITV0;  // P atomics committed (this wave)
      BAR;     // END

      if (hasC && tp < 32) {                     // out epoch s-5 (cpart via END barrier)
        float v = cb * sregv + bregv;
        #pragma unroll
        for (int p = 0; p < 8; ++p) v += cpart[p * 32 + tp];
        st4f_sc(a.out + ((size_t)(s - 5) * NIN + n0) * OUTN + oh + tp, v);
      }
      if (tp == 0) st4u_sc(a.pflags + bid, (unsigned)(s + 1));
    }
  }
}

extern "C" void kernel_launch(void* const* d_in, const int* in_sizes, int n_in,
                              void* d_out, int out_size, void* d_ws, size_t ws_size,
                              hipStream_t stream) {
  KArgs a;
  a.x     = (const float*)d_in[0];
  a.h0    = (const float*)d_in[1];
  a.W_ih  = (const float*)d_in[2];
  a.W_hh  = (const float*)d_in[3];
  a.b_ih  = (const float*)d_in[4];
  a.b_hh  = (const float*)d_in[5];
  a.W_hr  = (const float*)d_in[6];
  a.b_hr  = (const float*)d_in[7];
  a.W_reg = (const float*)d_in[8];
  a.b_reg = (const float*)d_in[9];
  a.out   = (float*)d_out;

  // Total footprint ~3.26 MB (proven-available). Flags at the FRONT.
  char* w = (char*)d_ws;
  a.hflags = (unsigned int*)w; w += 256 * 4;                           // 1 KB
  a.pflags = (unsigned int*)w; w += 256 * 4;                           // 1 KB
  a.Sreg   = (float*)w;        w += 256;                               // 256 B
  a.hb     = (ushort*)w;       w += (size_t)2 * T1N * HSN * 2;         // 1 MB
  a.Pbuf   = (float*)w;        w += (size_t)4 * 16384 * 4;             // 256 KB
  a.Ppart  = (ushort*)w;       w += (size_t)4 * 16 * 16384 * 2;        // 2 MB

  hipLaunchKernelGGL(gru_setup, dim3(64), dim3(256), 0, stream, a);
  hipLaunchKernelGGL(gru13, dim3(NBLK), dim3(NTHR), 0, stream, a);
}